// Round 7
// baseline (2567.128 us; speedup 1.0000x reference)
//
#include <hip/hip_runtime.h>
#include <hip/hip_bf16.h>

// RNN: h_t = tanh(x_t U + h_{t-1} W + b), return h_T.  B=256 T=512 D=K=256.
// SINGLE fused kernel: 16 blocks x 16 batch rows x 8 waves (32 cols/wave).
//  - W AND U live in VGPRs as MFMA B-frags for all 512 steps (64+64 VGPRs).
//  - h ping-pongs through LDS (proven R2/R6 layout, 528B rows).
//  - x_t U is computed one step AHEAD: during step t each wave streams the
//    x_{t+1} tile (16 rows x 256 d, shared across waves via L1) and folds it
//    into accx_next with 8 MFMAs; only 8 f32 regs cross the step boundary.
//    Step t's hW chain starts with C = accx_cur (xu_t), so no xu buffer, no
//    separate GEMM kernel, no transpose, no workspace, x read from HBM once.

typedef _Float16 half8_t __attribute__((ext_vector_type(8)));
typedef _Float16 half2_t __attribute__((ext_vector_type(2)));
typedef float    float4_t __attribute__((ext_vector_type(4)));

#define MFMA16(a, b, c) __builtin_amdgcn_mfma_f32_16x16x32_f16((a), (b), (c), 0, 0, 0)
// LDS-visibility barrier WITHOUT the vmcnt(0) drain (global loads stay in flight)
#define BARRIER_LGKM() asm volatile("s_waitcnt lgkmcnt(0)\n\ts_barrier" ::: "memory")

__device__ __forceinline__ half2_t pk_h2(float a, float b) {
    auto r = __builtin_amdgcn_cvt_pkrtz(a, b);
    return __builtin_bit_cast(half2_t, r);
}

__device__ __forceinline__ float fast_tanh(float x) {
    float e = __expf(2.0f * x);
    return 1.0f - 2.0f * __builtin_amdgcn_rcpf(e + 1.0f);
}

__global__ __launch_bounds__(512, 2) void rnn_fused(
    const float* __restrict__ x,        // [256][512][256] fp32
    const float* __restrict__ U,        // [256][256] fp32
    const float* __restrict__ W,        // [256][256] fp32
    const float* __restrict__ bias,     // [256]
    float* __restrict__ out)            // [256][256] fp32
{
    __shared__ char lds[16896];         // h dbuf: 2 x (16 rows x 528B)
    const int tid = threadIdx.x;
    const int lane = tid & 63, w = tid >> 6, l15 = lane & 15, q = lane >> 4;
    const int blk = blockIdx.x;
    const int c0 = 32 * w + 2 * l15;    // this lane's even column

    // ---- W and U -> register B-frags: frag[tt][c][j] = M[k=32c+8q+j][col=c0+tt]
    half8_t wf[2][8], uf[2][8];
#pragma unroll
    for (int tt = 0; tt < 2; ++tt)
#pragma unroll
        for (int c = 0; c < 8; ++c) {
            half8_t fw, fu;
#pragma unroll
            for (int j = 0; j < 8; ++j) {
                int k = 32 * c + q * 8 + j;
                fw[j] = (_Float16)W[k * 256 + c0 + tt];
                fu[j] = (_Float16)U[k * 256 + c0 + tt];
            }
            wf[tt][c] = fw;
            uf[tt][c] = fu;
        }
    const float b0 = bias[c0], b1 = bias[c0 + 1];

    // h0 = 0
    for (int i = tid; i < 16896 / 4; i += 512) ((int*)lds)[i] = 0;

    const int rowg0 = 16 * blk + 4 * q;             // this lane's C rows (+i)
    // x tile row for A-operand: row = 16*blk + l15; chunk c: d = 32c + 8q + j
    const float* xrow = x + ((size_t)(16 * blk + l15) * 512) * 256 + 8 * q;

    // compute accx for timestep t into (a0,a1): 16 loads + 8 MFMAs
    auto xu_acc = [&](int t, float4_t& a0, float4_t& a1) {
        const float* xp = xrow + (size_t)t * 256;
#pragma unroll
        for (int c = 0; c < 8; ++c) {
            float4 v0 = *(const float4*)(xp + 32 * c);
            float4 v1 = *(const float4*)(xp + 32 * c + 4);
            uint4 u;
            u.x = __builtin_bit_cast(unsigned, pk_h2(v0.x, v0.y));
            u.y = __builtin_bit_cast(unsigned, pk_h2(v0.z, v0.w));
            u.z = __builtin_bit_cast(unsigned, pk_h2(v1.x, v1.y));
            u.w = __builtin_bit_cast(unsigned, pk_h2(v1.z, v1.w));
            half8_t xa = __builtin_bit_cast(half8_t, u);
            a0 = MFMA16(xa, uf[0][c], a0);
            a1 = MFMA16(xa, uf[1][c], a1);
        }
    };

    float4_t axA0, axA1, axB0, axB1;
#pragma unroll
    for (int i = 0; i < 4; ++i) { axA0[i] = 0.f; axA1[i] = 0.f; }
    xu_acc(0, axA0, axA1);              // xu for t=0
    __syncthreads();                    // h0 zeros visible (full drain once)

    char* const hbuf0 = (char*)lds;
    char* const hbuf1 = (char*)lds + 8448;

    // one step: consumes (cx0,cx1)=xu_t, builds (nx0,nx1)=xu_{t+1}
    auto step = [&](int t, float4_t& cx0, float4_t& cx1,
                    float4_t& nx0, float4_t& nx1) {
#pragma unroll
        for (int i = 0; i < 4; ++i) { nx0[i] = 0.f; nx1[i] = 0.f; }
        xu_acc((t + 1) & 511, nx0, nx1);    // prefetch+fold next xu (off h path)

        const char* hcur = (t & 1) ? hbuf1 : hbuf0;
        half8_t af[8];
#pragma unroll
        for (int c = 0; c < 8; ++c)
            af[c] = *(const half8_t*)(hcur + l15 * 528 + c * 64 + q * 16);

        float4_t acc0 = cx0, acc1 = cx1;    // C init = xu_t (free)
#pragma unroll
        for (int c = 0; c < 8; ++c) {
            acc0 = MFMA16(af[c], wf[0][c], acc0);
            acc1 = MFMA16(af[c], wf[1][c], acc1);
        }

        if (t == 511) {
#pragma unroll
            for (int i = 0; i < 4; ++i) {
                float v0 = fast_tanh(acc0[i] + b0);
                float v1 = fast_tanh(acc1[i] + b1);
                float2 st; st.x = v0; st.y = v1;
                *(float2*)(&out[(rowg0 + i) * 256 + c0]) = st;
            }
        } else {
            char* hnext = ((t + 1) & 1) ? hbuf1 : hbuf0;
#pragma unroll
            for (int i = 0; i < 4; ++i) {
                float v0 = fast_tanh(acc0[i] + b0);
                float v1 = fast_tanh(acc1[i] + b1);
                *(half2_t*)(hnext + (4 * q + i) * 528 + c0 * 2) = pk_h2(v0, v1);
            }
            BARRIER_LGKM();                 // LDS-only sync; x loads in flight
        }
    };

    for (int t2 = 0; t2 < 512; t2 += 2) {
        step(t2,     axA0, axA1, axB0, axB1);
        step(t2 + 1, axB0, axB1, axA0, axA1);
    }
}

extern "C" void kernel_launch(void* const* d_in, const int* in_sizes, int n_in,
                              void* d_out, int out_size, void* d_ws, size_t ws_size,
                              hipStream_t stream) {
    const float* x = (const float*)d_in[0];   // [256,512,256]
    const float* U = (const float*)d_in[1];   // [256,256]
    const float* W = (const float*)d_in[2];   // [256,256]
    const float* b = (const float*)d_in[3];   // [256]
    float* out = (float*)d_out;
    (void)d_ws; (void)ws_size;                // no workspace needed

    rnn_fused<<<16, 512, 0, stream>>>(x, U, W, b, out);
}